// Round 4
// baseline (221.083 us; speedup 1.0000x reference)
//
#include <hip/hip_runtime.h>
#include <hip/hip_bf16.h>

#define SEQL 2048
#define DMODEL 1024

typedef short bf16x8 __attribute__((ext_vector_type(8)));
typedef short bf16x4 __attribute__((ext_vector_type(4)));
typedef float f32x4 __attribute__((ext_vector_type(4)));
typedef unsigned short u16;

__device__ __forceinline__ u16 f2bf(float f) {
    union { float f; unsigned u; } v; v.f = f;
    unsigned r = v.u + 0x7FFFu + ((v.u >> 16) & 1u);
    return (u16)(r >> 16);
}

// ---------- pack everything in one launch ----------
// b < 2048   : K fp32 [n][s][h*64+d] -> bf16 [n][h][s][d]
// b < 2560   : W fp32 -> bf16 flat
// b < 3584   : V fp32 [n][s][h*64+d] -> bf16 transposed [n][h][d][s]
// b == 3584  : mask int -> additive bias float (0 or -1e5)
__global__ __launch_bounds__(256) void pack_all(
    const float* __restrict__ kg, const float* __restrict__ wg,
    const float* __restrict__ vg, const int* __restrict__ mg,
    u16* __restrict__ kb, u16* __restrict__ wb, u16* __restrict__ vtb,
    float* __restrict__ maskf)
{
    __shared__ __align__(16) u16 T[64 * 72];
    const int b = blockIdx.x, t = threadIdx.x;
    u16 o[8];
    if (b < 2048) {
        const int e0 = (b * 256 + t) * 8;
        const int n = e0 >> 21, rem = e0 & ((1 << 21) - 1);
        const int s = rem >> 10, dm = rem & 1023, h = dm >> 6, d = dm & 63;
        const float4 x0 = *(const float4*)(kg + e0);
        const float4 x1 = *(const float4*)(kg + e0 + 4);
        o[0]=f2bf(x0.x); o[1]=f2bf(x0.y); o[2]=f2bf(x0.z); o[3]=f2bf(x0.w);
        o[4]=f2bf(x1.x); o[5]=f2bf(x1.y); o[6]=f2bf(x1.z); o[7]=f2bf(x1.w);
        *(bf16x8*)(kb + ((((size_t)n * 16 + h) * 2048 + s) * 64 + d)) = *(bf16x8*)o;
    } else if (b < 2560) {
        const int e0 = ((b - 2048) * 256 + t) * 8;
        const float4 x0 = *(const float4*)(wg + e0);
        const float4 x1 = *(const float4*)(wg + e0 + 4);
        o[0]=f2bf(x0.x); o[1]=f2bf(x0.y); o[2]=f2bf(x0.z); o[3]=f2bf(x0.w);
        o[4]=f2bf(x1.x); o[5]=f2bf(x1.y); o[6]=f2bf(x1.z); o[7]=f2bf(x1.w);
        *(bf16x8*)(wb + e0) = *(bf16x8*)o;
    } else if (b < 3584) {
        const int bb = b - 2560;
        const int st = bb & 31, h = (bb >> 5) & 15, n = bb >> 9;
        {
            const int s = t >> 2, d0 = (t & 3) * 16;
            const float* src = vg + ((size_t)(n * SEQL + st * 64 + s) * DMODEL) + h * 64 + d0;
            u16 w16[16];
            #pragma unroll
            for (int j = 0; j < 16; ++j) w16[j] = f2bf(src[j]);
            *(bf16x8*)&T[s * 72 + d0]     = *(bf16x8*)&w16[0];
            *(bf16x8*)&T[s * 72 + d0 + 8] = *(bf16x8*)&w16[8];
        }
        __syncthreads();
        {
            const int d = t >> 2, k0 = (t & 3) * 16;
            u16 w16[16];
            #pragma unroll
            for (int j = 0; j < 16; ++j) w16[j] = T[(k0 + j) * 72 + d];
            u16* dst = vtb + ((size_t)((n * 16 + h) * 64 + d) * SEQL) + st * 64 + k0;
            *(bf16x8*)dst       = *(bf16x8*)&w16[0];
            *(bf16x8*)(dst + 8) = *(bf16x8*)&w16[8];
        }
    } else {
        #pragma unroll
        for (int i = 0; i < 16; ++i) {
            const int idx = t * 16 + i;
            maskf[idx] = mg[idx] ? 0.0f : -1.0e5f;
        }
    }
}

// ---------- attention: QT=128, KT=64, S^T trick, streaming softmax, split-K ----------
#define KSTR 72
#define VSTR 72
#define PT 72
#define OSPLIT 4194304   // fp32 elems per O-partial split
#define LSPLIT 65536     // fp32 elems per l-partial split

template<int NSPLIT>
__global__ __launch_bounds__(256) void attn_kernel(
    const float* __restrict__ qg, const u16* __restrict__ kb,
    const u16* __restrict__ vtb, const float* __restrict__ maskf,
    u16* __restrict__ xb, float* __restrict__ opart, float* __restrict__ lpart)
{
    __shared__ __align__(16) u16 K_lds[64 * KSTR];    // [key][d]
    __shared__ __align__(16) u16 Vt_lds[64 * VSTR];   // [d][key]
    __shared__ __align__(16) u16 P_lds[128 * PT];     // [q 128][key 64+pad]

    const int blk = blockIdx.x;            // qblk(16) x h(16) x n(2) x split
    const int qblk = blk & 15;
    const int h = (blk >> 4) & 15;
    const int n = (blk >> 8) & 1;
    const int split = blk >> 9;
    const int tid = threadIdx.x;
    const int wave = tid >> 6, lane = tid & 63;
    const int lrow = lane & 15, quad = lane >> 4;
    const int q0 = qblk * 128;

    // Q fragments (B-operand layout [q=lane&15][d=quad*8+j]); 2 q-tiles per wave
    bf16x8 qf[2][2];
    #pragma unroll
    for (int qi = 0; qi < 2; ++qi) {
        const float* qp = qg + ((size_t)(n * SEQL + q0 + wave * 32 + qi * 16 + lrow) * DMODEL) + h * 64 + quad * 8;
        #pragma unroll
        for (int f = 0; f < 2; ++f) {
            const float4 a = *(const float4*)(qp + f * 32);
            const float4 c = *(const float4*)(qp + f * 32 + 4);
            u16* dst = (u16*)&qf[qi][f];
            dst[0]=f2bf(a.x); dst[1]=f2bf(a.y); dst[2]=f2bf(a.z); dst[3]=f2bf(a.w);
            dst[4]=f2bf(c.x); dst[5]=f2bf(c.y); dst[6]=f2bf(c.z); dst[7]=f2bf(c.w);
        }
    }

    bf16x8 onesf;
    #pragma unroll
    for (int j = 0; j < 8; ++j) ((u16*)&onesf)[j] = 0x3F80;

    f32x4 oacc[2][4];
    f32x4 lacc[2];
    #pragma unroll
    for (int qi = 0; qi < 2; ++qi) {
        lacc[qi] = (f32x4){0.f, 0.f, 0.f, 0.f};
        #pragma unroll
        for (int t4 = 0; t4 < 4; ++t4) oacc[qi][t4] = (f32x4){0.f, 0.f, 0.f, 0.f};
    }

    const u16* ksrc0 = kb  + ((size_t)(n * 16 + h) * SEQL) * 64;
    const u16* vsrc0 = vtb + ((size_t)(n * 16 + h) * 64) * SEQL;
    const float* mrow = maskf + n * SEQL;

    const int ktlo = split * (32 / NSPLIT);
    const int kthi = ktlo + (32 / NSPLIT);

    for (int kt = ktlo; kt < kthi; ++kt) {
        __syncthreads();
        {
            const u16* ks = ksrc0 + (size_t)kt * 64 * 64;
            const u16* vs = vsrc0 + kt * 64;
            #pragma unroll
            for (int i = 0; i < 2; ++i) {
                const int c = tid + i * 256;
                const int r = c >> 3, e0 = (c & 7) * 8;
                *(bf16x8*)&K_lds[r * KSTR + e0]  = *(const bf16x8*)(ks + c * 8);
                *(bf16x8*)&Vt_lds[r * VSTR + e0] = *(const bf16x8*)(vs + (size_t)r * SEQL + e0);
            }
        }
        __syncthreads();

        // S^T = K Q^T : C col = q (lane&15), C rows = key (quad*4+r)
        #pragma unroll
        for (int st = 0; st < 4; ++st) {
            const bf16x8 kf0 = *(const bf16x8*)&K_lds[(st * 16 + lrow) * KSTR + quad * 8];
            const bf16x8 kf1 = *(const bf16x8*)&K_lds[(st * 16 + lrow) * KSTR + 32 + quad * 8];
            const f32x4 mv = *(const f32x4*)&mrow[kt * 64 + st * 16 + quad * 4];
            #pragma unroll
            for (int qi = 0; qi < 2; ++qi) {
                f32x4 sa = (f32x4){0.f, 0.f, 0.f, 0.f};
                sa = __builtin_amdgcn_mfma_f32_16x16x32_bf16(kf0, qf[qi][0], sa, 0, 0, 0);
                sa = __builtin_amdgcn_mfma_f32_16x16x32_bf16(kf1, qf[qi][1], sa, 0, 0, 0);
                // additive mask bias folded into exp argument (mv = 0 or -1e5)
                float e0v = __expf(fmaf(sa[0], 0.03125f, mv[0]));
                float e1v = __expf(fmaf(sa[1], 0.03125f, mv[1]));
                float e2v = __expf(fmaf(sa[2], 0.03125f, mv[2]));
                float e3v = __expf(fmaf(sa[3], 0.03125f, mv[3]));
                __hip_bfloat162 h0 = __float22bfloat162_rn(make_float2(e0v, e1v));
                __hip_bfloat162 h1 = __float22bfloat162_rn(make_float2(e2v, e3v));
                union { unsigned u[2]; bf16x4 v; } pk;
                pk.u[0] = *(unsigned*)&h0;
                pk.u[1] = *(unsigned*)&h1;
                *(bf16x4*)&P_lds[(wave * 32 + qi * 16 + lrow) * PT + st * 16 + quad * 4] = pk.v;
            }
        }
        asm volatile("s_waitcnt lgkmcnt(0)" ::: "memory");

        bf16x8 vf[4][2];
        #pragma unroll
        for (int t4 = 0; t4 < 4; ++t4) {
            vf[t4][0] = *(const bf16x8*)&Vt_lds[(t4 * 16 + lrow) * VSTR + quad * 8];
            vf[t4][1] = *(const bf16x8*)&Vt_lds[(t4 * 16 + lrow) * VSTR + 32 + quad * 8];
        }
        #pragma unroll
        for (int qi = 0; qi < 2; ++qi) {
            const int prow = (wave * 32 + qi * 16 + lrow) * PT;
            const bf16x8 pf0 = *(const bf16x8*)&P_lds[prow + quad * 8];
            const bf16x8 pf1 = *(const bf16x8*)&P_lds[prow + 32 + quad * 8];
            lacc[qi] = __builtin_amdgcn_mfma_f32_16x16x32_bf16(pf0, onesf, lacc[qi], 0, 0, 0);
            lacc[qi] = __builtin_amdgcn_mfma_f32_16x16x32_bf16(pf1, onesf, lacc[qi], 0, 0, 0);
            #pragma unroll
            for (int t4 = 0; t4 < 4; ++t4) {
                oacc[qi][t4] = __builtin_amdgcn_mfma_f32_16x16x32_bf16(pf0, vf[t4][0], oacc[qi][t4], 0, 0, 0);
                oacc[qi][t4] = __builtin_amdgcn_mfma_f32_16x16x32_bf16(pf1, vf[t4][1], oacc[qi][t4], 0, 0, 0);
            }
        }
    }

    if (NSPLIT == 1) {
        #pragma unroll
        for (int qi = 0; qi < 2; ++qi)
            #pragma unroll
            for (int r = 0; r < 4; ++r) {
                const float rinv = 1.0f / lacc[qi][r];
                const int q = q0 + wave * 32 + qi * 16 + quad * 4 + r;
                u16* op = xb + (size_t)(n * SEQL + q) * DMODEL + h * 64 + lrow;
                #pragma unroll
                for (int t4 = 0; t4 < 4; ++t4)
                    op[t4 * 16] = f2bf(oacc[qi][t4][r] * rinv);
            }
    } else {
        #pragma unroll
        for (int qi = 0; qi < 2; ++qi) {
            #pragma unroll
            for (int r = 0; r < 4; ++r) {
                const int q = q0 + wave * 32 + qi * 16 + quad * 4 + r;
                float* op = opart + (size_t)split * OSPLIT + (size_t)(n * SEQL + q) * DMODEL + h * 64 + lrow;
                #pragma unroll
                for (int t4 = 0; t4 < 4; ++t4)
                    op[t4 * 16] = oacc[qi][t4][r];
                if (lrow == 0)
                    lpart[split * LSPLIT + (n * SEQL + q) * 16 + h] = lacc[qi][r];
            }
        }
    }
}

// ---------- FC: out = X @ W^T + b, 128x64 tile, BK=64, optional fused reduce+norm ----------
// FUSED: X-tile is built from opart(split0)+opart(split1), normalized by
// 1/(l0+l1). With BK=64 the k-range of tile kt is exactly head h=kt, so the
// l-lookup is one scalar pair per row per kt.
#define FSTR 72

template<bool FUSED>
__global__ __launch_bounds__(256) void fc_kernel(
    const u16* __restrict__ xb, const float* __restrict__ opart,
    const float* __restrict__ lpart, const u16* __restrict__ wb,
    const float* __restrict__ bias, float* __restrict__ out)
{
    __shared__ __align__(16) u16 X_lds[128 * FSTR];
    __shared__ __align__(16) u16 W_lds[64 * FSTR];

    const int blk = blockIdx.x;          // 32 rowblocks x 16 colblocks = 512
    const int cb = blk & 15, rb = blk >> 4;
    const int row0 = rb * 128, col0 = cb * 64;
    const int tid = threadIdx.x;
    const int wave = tid >> 6, lane = tid & 63;
    const int lrow = lane & 15, quad = lane >> 4;

    f32x4 acc[2][4];
    #pragma unroll
    for (int ri = 0; ri < 2; ++ri)
        #pragma unroll
        for (int cj = 0; cj < 4; ++cj) acc[ri][cj] = (f32x4){0.f, 0.f, 0.f, 0.f};

    for (int kt = 0; kt < 16; ++kt) {
        __syncthreads();
        // stage X: 128 rows x 64 k = 1024 groups of 8
        #pragma unroll
        for (int i = 0; i < 4; ++i) {
            const int g = tid + i * 256;
            const int r = g >> 3, e0 = (g & 7) * 8;
            if (FUSED) {
                const float* p0 = opart + (size_t)(row0 + r) * DMODEL + kt * 64 + e0;
                const float4 a0 = *(const float4*)p0;
                const float4 a1 = *(const float4*)(p0 + 4);
                const float4 b0 = *(const float4*)(p0 + OSPLIT);
                const float4 b1 = *(const float4*)(p0 + OSPLIT + 4);
                const float ri_ = __frcp_rn(lpart[(row0 + r) * 16 + kt] +
                                            lpart[LSPLIT + (row0 + r) * 16 + kt]);
                u16 o[8];
                o[0] = f2bf((a0.x + b0.x) * ri_); o[1] = f2bf((a0.y + b0.y) * ri_);
                o[2] = f2bf((a0.z + b0.z) * ri_); o[3] = f2bf((a0.w + b0.w) * ri_);
                o[4] = f2bf((a1.x + b1.x) * ri_); o[5] = f2bf((a1.y + b1.y) * ri_);
                o[6] = f2bf((a1.z + b1.z) * ri_); o[7] = f2bf((a1.w + b1.w) * ri_);
                *(bf16x8*)&X_lds[r * FSTR + e0] = *(bf16x8*)o;
            } else {
                *(bf16x8*)&X_lds[r * FSTR + e0] =
                    *(const bf16x8*)(xb + (size_t)(row0 + r) * DMODEL + kt * 64 + e0);
            }
        }
        // stage W: 64 rows x 64 k = 512 groups of 8
        #pragma unroll
        for (int i = 0; i < 2; ++i) {
            const int g = tid + i * 256;
            const int r = g >> 3, e0 = (g & 7) * 8;
            *(bf16x8*)&W_lds[r * FSTR + e0] =
                *(const bf16x8*)(wb + (size_t)(col0 + r) * DMODEL + kt * 64 + e0);
        }
        __syncthreads();

        bf16x8 af[2][2];
        #pragma unroll
        for (int ri = 0; ri < 2; ++ri) {
            af[ri][0] = *(const bf16x8*)&X_lds[(wave * 32 + ri * 16 + lrow) * FSTR + quad * 8];
            af[ri][1] = *(const bf16x8*)&X_lds[(wave * 32 + ri * 16 + lrow) * FSTR + 32 + quad * 8];
        }
        #pragma unroll
        for (int cj = 0; cj < 4; ++cj) {
            const bf16x8 bf0 = *(const bf16x8*)&W_lds[(cj * 16 + lrow) * FSTR + quad * 8];
            const bf16x8 bf1 = *(const bf16x8*)&W_lds[(cj * 16 + lrow) * FSTR + 32 + quad * 8];
            #pragma unroll
            for (int ri = 0; ri < 2; ++ri) {
                acc[ri][cj] = __builtin_amdgcn_mfma_f32_16x16x32_bf16(af[ri][0], bf0, acc[ri][cj], 0, 0, 0);
                acc[ri][cj] = __builtin_amdgcn_mfma_f32_16x16x32_bf16(af[ri][1], bf1, acc[ri][cj], 0, 0, 0);
            }
        }
    }

    #pragma unroll
    for (int ri = 0; ri < 2; ++ri)
        #pragma unroll
        for (int cj = 0; cj < 4; ++cj) {
            const int col = col0 + cj * 16 + lrow;
            const float bv = bias[col];
            #pragma unroll
            for (int r = 0; r < 4; ++r)
                out[(size_t)(row0 + wave * 32 + ri * 16 + quad * 4 + r) * DMODEL + col] = acc[ri][cj][r] + bv;
        }
}

extern "C" void kernel_launch(void* const* d_in, const int* in_sizes, int n_in,
                              void* d_out, int out_size, void* d_ws, size_t ws_size,
                              hipStream_t stream) {
    const float* q   = (const float*)d_in[0];
    const float* k   = (const float*)d_in[1];
    const float* v   = (const float*)d_in[2];
    const int*   m   = (const int*)d_in[3];
    const float* fcw = (const float*)d_in[4];
    const float* fcb = (const float*)d_in[5];
    float* out = (float*)d_out;

    char* ws = (char*)d_ws;
    u16*   kbuf  = (u16*)(ws);                     // 8 MB  bf16 [2][16][2048][64]
    u16*   vtbuf = (u16*)(ws + (8u  << 20));       // 8 MB  bf16 [2][16][64][2048]
    u16*   wbuf  = (u16*)(ws + (16u << 20));       // 2 MB  bf16 [1024][1024]
    u16*   xbuf  = (u16*)(ws + (18u << 20));       // 8 MB  bf16 [4096][1024] (fallback only)
    float* maskf = (float*)(ws + (26u << 20));     // 16 KB float bias [2][2048]
    float* opart = (float*)(ws + (27u << 20));     // 32 MB fp32 [2][4096][1024]
    float* lpart = (float*)(ws + (59u << 20));     // 512 KB fp32 [2][4096][16]
    const bool split2 = ws_size >= (60u << 20);

    pack_all<<<dim3(3585), dim3(256), 0, stream>>>(k, fcw, v, m, kbuf, wbuf, vtbuf, maskf);
    if (split2) {
        attn_kernel<2><<<dim3(1024), dim3(256), 0, stream>>>(q, kbuf, vtbuf, maskf, xbuf, opart, lpart);
        fc_kernel<true><<<dim3(512), dim3(256), 0, stream>>>(xbuf, opart, lpart, wbuf, fcb, out);
    } else {
        attn_kernel<1><<<dim3(512), dim3(256), 0, stream>>>(q, kbuf, vtbuf, maskf, xbuf, opart, lpart);
        fc_kernel<false><<<dim3(512), dim3(256), 0, stream>>>(xbuf, opart, lpart, wbuf, fcb, out);
    }
}

// Round 5
// 210.151 us; speedup vs baseline: 1.0520x; 1.0520x over previous
//
#include <hip/hip_runtime.h>
#include <hip/hip_bf16.h>

#define SEQL 2048
#define DMODEL 1024

typedef short bf16x8 __attribute__((ext_vector_type(8)));
typedef short bf16x4 __attribute__((ext_vector_type(4)));
typedef float f32x4 __attribute__((ext_vector_type(4)));
typedef unsigned short u16;

__device__ __forceinline__ u16 f2bf(float f) {
    union { float f; unsigned u; } v; v.f = f;
    unsigned r = v.u + 0x7FFFu + ((v.u >> 16) & 1u);
    return (u16)(r >> 16);
}

// ---------- pack everything in one launch ----------
// b < 2048   : K fp32 [n][s][h*64+d] -> bf16 [n][h][s][d]
// b < 2560   : W fp32 -> bf16 flat
// b < 3584   : V fp32 [n][s][h*64+d] -> bf16 transposed [n][h][d][s]
// b == 3584  : mask int -> additive bias float (0 or -1e5)
#define TSTR 66   // transpose-tile stride: 33 dwords -> 2-way banks (free)

__global__ __launch_bounds__(256) void pack_all(
    const float* __restrict__ kg, const float* __restrict__ wg,
    const float* __restrict__ vg, const int* __restrict__ mg,
    u16* __restrict__ kb, u16* __restrict__ wb, u16* __restrict__ vtb,
    float* __restrict__ maskf)
{
    __shared__ __align__(16) u16 T[64 * TSTR];
    const int b = blockIdx.x, t = threadIdx.x;
    u16 o[8];
    if (b < 2048) {
        const int e0 = (b * 256 + t) * 8;
        const int n = e0 >> 21, rem = e0 & ((1 << 21) - 1);
        const int s = rem >> 10, dm = rem & 1023, h = dm >> 6, d = dm & 63;
        const float4 x0 = *(const float4*)(kg + e0);
        const float4 x1 = *(const float4*)(kg + e0 + 4);
        o[0]=f2bf(x0.x); o[1]=f2bf(x0.y); o[2]=f2bf(x0.z); o[3]=f2bf(x0.w);
        o[4]=f2bf(x1.x); o[5]=f2bf(x1.y); o[6]=f2bf(x1.z); o[7]=f2bf(x1.w);
        *(bf16x8*)(kb + ((((size_t)n * 16 + h) * 2048 + s) * 64 + d)) = *(bf16x8*)o;
    } else if (b < 2560) {
        const int e0 = ((b - 2048) * 256 + t) * 8;
        const float4 x0 = *(const float4*)(wg + e0);
        const float4 x1 = *(const float4*)(wg + e0 + 4);
        o[0]=f2bf(x0.x); o[1]=f2bf(x0.y); o[2]=f2bf(x0.z); o[3]=f2bf(x0.w);
        o[4]=f2bf(x1.x); o[5]=f2bf(x1.y); o[6]=f2bf(x1.z); o[7]=f2bf(x1.w);
        *(bf16x8*)(wb + e0) = *(bf16x8*)o;
    } else if (b < 3584) {
        const int bb = b - 2560;
        const int st = bb & 31, h = (bb >> 5) & 15, n = bb >> 9;
        {
            const int s = t >> 2, d0 = (t & 3) * 16;
            const float* src = vg + ((size_t)(n * SEQL + st * 64 + s) * DMODEL) + h * 64 + d0;
            u16 w16[16];
            #pragma unroll
            for (int j = 0; j < 16; ++j) w16[j] = f2bf(src[j]);
            *(bf16x8*)&T[s * TSTR + d0]     = *(bf16x8*)&w16[0];
            *(bf16x8*)&T[s * TSTR + d0 + 8] = *(bf16x8*)&w16[8];
        }
        __syncthreads();
        {
            const int d = t >> 2, k0 = (t & 3) * 16;
            u16 w16[16];
            #pragma unroll
            for (int j = 0; j < 16; ++j) w16[j] = T[(k0 + j) * TSTR + d];
            u16* dst = vtb + ((size_t)((n * 16 + h) * 64 + d) * SEQL) + st * 64 + k0;
            *(bf16x8*)dst       = *(bf16x8*)&w16[0];
            *(bf16x8*)(dst + 8) = *(bf16x8*)&w16[8];
        }
    } else {
        #pragma unroll
        for (int i = 0; i < 16; ++i) {
            const int idx = t * 16 + i;
            maskf[idx] = mg[idx] ? 0.0f : -1.0e5f;
        }
    }
}

// ---------- attention: QT=128, KT=64, S^T trick, streaming softmax, split-K ----------
// strides 66 (33 dwords): frag b128 reads land on (lrow + 8*quad) mod 32 -> 2-way (free)
#define KSTR 66
#define VSTR 66
#define PT 66
#define OSPLIT 4194304   // fp32 elems per O-partial split (16 MB)
#define LSPLIT 65536     // fp32 elems per l-partial split

template<int NSPLIT>
__global__ __launch_bounds__(256) void attn_kernel(
    const float* __restrict__ qg, const u16* __restrict__ kb,
    const u16* __restrict__ vtb, const float* __restrict__ maskf,
    u16* __restrict__ xb, float* __restrict__ opart, float* __restrict__ lpart)
{
    __shared__ __align__(16) u16 K_lds[64 * KSTR];    // [key][d]
    __shared__ __align__(16) u16 Vt_lds[64 * VSTR];   // [d][key]
    __shared__ __align__(16) u16 P_lds[128 * PT];     // [q 128][key 64+pad]

    const int blk = blockIdx.x;            // qblk(16) x h(16) x n(2) x split
    const int qblk = blk & 15;
    const int h = (blk >> 4) & 15;
    const int n = (blk >> 8) & 1;
    const int split = blk >> 9;
    const int tid = threadIdx.x;
    const int wave = tid >> 6, lane = tid & 63;
    const int lrow = lane & 15, quad = lane >> 4;
    const int q0 = qblk * 128;

    // Q fragments (B-operand layout [q=lane&15][d=quad*8+j]); 2 q-tiles per wave
    bf16x8 qf[2][2];
    #pragma unroll
    for (int qi = 0; qi < 2; ++qi) {
        const float* qp = qg + ((size_t)(n * SEQL + q0 + wave * 32 + qi * 16 + lrow) * DMODEL) + h * 64 + quad * 8;
        #pragma unroll
        for (int f = 0; f < 2; ++f) {
            const float4 a = *(const float4*)(qp + f * 32);
            const float4 c = *(const float4*)(qp + f * 32 + 4);
            u16* dst = (u16*)&qf[qi][f];
            dst[0]=f2bf(a.x); dst[1]=f2bf(a.y); dst[2]=f2bf(a.z); dst[3]=f2bf(a.w);
            dst[4]=f2bf(c.x); dst[5]=f2bf(c.y); dst[6]=f2bf(c.z); dst[7]=f2bf(c.w);
        }
    }

    bf16x8 onesf;
    #pragma unroll
    for (int j = 0; j < 8; ++j) ((u16*)&onesf)[j] = 0x3F80;

    f32x4 oacc[2][4];
    f32x4 lacc[2];
    #pragma unroll
    for (int qi = 0; qi < 2; ++qi) {
        lacc[qi] = (f32x4){0.f, 0.f, 0.f, 0.f};
        #pragma unroll
        for (int t4 = 0; t4 < 4; ++t4) oacc[qi][t4] = (f32x4){0.f, 0.f, 0.f, 0.f};
    }

    const u16* ksrc0 = kb  + ((size_t)(n * 16 + h) * SEQL) * 64;
    const u16* vsrc0 = vtb + ((size_t)(n * 16 + h) * 64) * SEQL;
    const float* mrow = maskf + n * SEQL;

    const int ktlo = split * (32 / NSPLIT);
    const int kthi = ktlo + (32 / NSPLIT);

    for (int kt = ktlo; kt < kthi; ++kt) {
        __syncthreads();
        {
            const u16* ks = ksrc0 + (size_t)kt * 64 * 64;
            const u16* vs = vsrc0 + kt * 64;
            #pragma unroll
            for (int i = 0; i < 2; ++i) {
                const int c = tid + i * 256;
                const int r = c >> 3, e0 = (c & 7) * 8;
                *(bf16x8*)&K_lds[r * KSTR + e0]  = *(const bf16x8*)(ks + c * 8);
                *(bf16x8*)&Vt_lds[r * VSTR + e0] = *(const bf16x8*)(vs + (size_t)r * SEQL + e0);
            }
        }
        __syncthreads();

        // S^T = K Q^T : C col = q (lane&15), C rows = key (quad*4+r)
        #pragma unroll
        for (int st = 0; st < 4; ++st) {
            const bf16x8 kf0 = *(const bf16x8*)&K_lds[(st * 16 + lrow) * KSTR + quad * 8];
            const bf16x8 kf1 = *(const bf16x8*)&K_lds[(st * 16 + lrow) * KSTR + 32 + quad * 8];
            const f32x4 mv = *(const f32x4*)&mrow[kt * 64 + st * 16 + quad * 4];
            #pragma unroll
            for (int qi = 0; qi < 2; ++qi) {
                f32x4 sa = (f32x4){0.f, 0.f, 0.f, 0.f};
                sa = __builtin_amdgcn_mfma_f32_16x16x32_bf16(kf0, qf[qi][0], sa, 0, 0, 0);
                sa = __builtin_amdgcn_mfma_f32_16x16x32_bf16(kf1, qf[qi][1], sa, 0, 0, 0);
                // additive mask bias folded into exp argument (mv = 0 or -1e5)
                float e0v = __expf(fmaf(sa[0], 0.03125f, mv[0]));
                float e1v = __expf(fmaf(sa[1], 0.03125f, mv[1]));
                float e2v = __expf(fmaf(sa[2], 0.03125f, mv[2]));
                float e3v = __expf(fmaf(sa[3], 0.03125f, mv[3]));
                __hip_bfloat162 h0 = __float22bfloat162_rn(make_float2(e0v, e1v));
                __hip_bfloat162 h1 = __float22bfloat162_rn(make_float2(e2v, e3v));
                union { unsigned u[2]; bf16x4 v; } pk;
                pk.u[0] = *(unsigned*)&h0;
                pk.u[1] = *(unsigned*)&h1;
                *(bf16x4*)&P_lds[(wave * 32 + qi * 16 + lrow) * PT + st * 16 + quad * 4] = pk.v;
            }
        }
        asm volatile("s_waitcnt lgkmcnt(0)" ::: "memory");

        bf16x8 vf[4][2];
        #pragma unroll
        for (int t4 = 0; t4 < 4; ++t4) {
            vf[t4][0] = *(const bf16x8*)&Vt_lds[(t4 * 16 + lrow) * VSTR + quad * 8];
            vf[t4][1] = *(const bf16x8*)&Vt_lds[(t4 * 16 + lrow) * VSTR + 32 + quad * 8];
        }
        #pragma unroll
        for (int qi = 0; qi < 2; ++qi) {
            const int prow = (wave * 32 + qi * 16 + lrow) * PT;
            const bf16x8 pf0 = *(const bf16x8*)&P_lds[prow + quad * 8];
            const bf16x8 pf1 = *(const bf16x8*)&P_lds[prow + 32 + quad * 8];
            lacc[qi] = __builtin_amdgcn_mfma_f32_16x16x32_bf16(pf0, onesf, lacc[qi], 0, 0, 0);
            lacc[qi] = __builtin_amdgcn_mfma_f32_16x16x32_bf16(pf1, onesf, lacc[qi], 0, 0, 0);
            #pragma unroll
            for (int t4 = 0; t4 < 4; ++t4) {
                oacc[qi][t4] = __builtin_amdgcn_mfma_f32_16x16x32_bf16(pf0, vf[t4][0], oacc[qi][t4], 0, 0, 0);
                oacc[qi][t4] = __builtin_amdgcn_mfma_f32_16x16x32_bf16(pf1, vf[t4][1], oacc[qi][t4], 0, 0, 0);
            }
        }
    }

    if (NSPLIT == 1) {
        #pragma unroll
        for (int qi = 0; qi < 2; ++qi)
            #pragma unroll
            for (int r = 0; r < 4; ++r) {
                const float rinv = 1.0f / lacc[qi][r];
                const int q = q0 + wave * 32 + qi * 16 + quad * 4 + r;
                u16* op = xb + (size_t)(n * SEQL + q) * DMODEL + h * 64 + lrow;
                #pragma unroll
                for (int t4 = 0; t4 < 4; ++t4)
                    op[t4 * 16] = f2bf(oacc[qi][t4][r] * rinv);
            }
    } else {
        #pragma unroll
        for (int qi = 0; qi < 2; ++qi) {
            #pragma unroll
            for (int r = 0; r < 4; ++r) {
                const int q = q0 + wave * 32 + qi * 16 + quad * 4 + r;
                float* op = opart + (size_t)split * OSPLIT + (size_t)(n * SEQL + q) * DMODEL + h * 64 + lrow;
                #pragma unroll
                for (int t4 = 0; t4 < 4; ++t4)
                    op[t4 * 16] = oacc[qi][t4][r];
                if (lrow == 0)
                    lpart[split * LSPLIT + (n * SEQL + q) * 16 + h] = lacc[qi][r];
            }
        }
    }
}

// ---------- split-K reduce + normalize -> bf16 X (ONCE, not per fc col-block) ----------
template<int NSPLIT>
__global__ __launch_bounds__(256) void reduce_norm(
    const float* __restrict__ opart, const float* __restrict__ lpart,
    u16* __restrict__ xb)
{
    const int gid = blockIdx.x * 256 + threadIdx.x;   // 524288 threads
    const int e0 = gid * 8;
    const int row = e0 >> 10, c = e0 & 1023, h = c >> 6;
    float lsum = 0.f;
    #pragma unroll
    for (int s = 0; s < NSPLIT; ++s) lsum += lpart[s * LSPLIT + row * 16 + h];
    const float rinv = 1.0f / lsum;
    float a[8] = {0.f,0.f,0.f,0.f,0.f,0.f,0.f,0.f};
    #pragma unroll
    for (int s = 0; s < NSPLIT; ++s) {
        const float4 x0 = *(const float4*)(opart + (size_t)s * OSPLIT + e0);
        const float4 x1 = *(const float4*)(opart + (size_t)s * OSPLIT + e0 + 4);
        a[0]+=x0.x; a[1]+=x0.y; a[2]+=x0.z; a[3]+=x0.w;
        a[4]+=x1.x; a[5]+=x1.y; a[6]+=x1.z; a[7]+=x1.w;
    }
    u16 o[8];
    #pragma unroll
    for (int j = 0; j < 8; ++j) o[j] = f2bf(a[j] * rinv);
    *(bf16x8*)(xb + e0) = *(bf16x8*)o;
}

// ---------- FC: out = X @ W^T + b, 128x64 tile, BK=64 ----------
#define FSTR 66

__global__ __launch_bounds__(256) void fc_kernel(
    const u16* __restrict__ xb, const u16* __restrict__ wb,
    const float* __restrict__ bias, float* __restrict__ out)
{
    __shared__ __align__(16) u16 X_lds[128 * FSTR];
    __shared__ __align__(16) u16 W_lds[64 * FSTR];

    const int blk = blockIdx.x;          // 32 rowblocks x 16 colblocks = 512
    const int cb = blk & 15, rb = blk >> 4;
    const int row0 = rb * 128, col0 = cb * 64;
    const int tid = threadIdx.x;
    const int wave = tid >> 6, lane = tid & 63;
    const int lrow = lane & 15, quad = lane >> 4;

    f32x4 acc[2][4];
    #pragma unroll
    for (int ri = 0; ri < 2; ++ri)
        #pragma unroll
        for (int cj = 0; cj < 4; ++cj) acc[ri][cj] = (f32x4){0.f, 0.f, 0.f, 0.f};

    for (int kt = 0; kt < 16; ++kt) {
        __syncthreads();
        #pragma unroll
        for (int i = 0; i < 4; ++i) {
            const int g = tid + i * 256;
            const int r = g >> 3, e0 = (g & 7) * 8;
            *(bf16x8*)&X_lds[r * FSTR + e0] =
                *(const bf16x8*)(xb + (size_t)(row0 + r) * DMODEL + kt * 64 + e0);
        }
        #pragma unroll
        for (int i = 0; i < 2; ++i) {
            const int g = tid + i * 256;
            const int r = g >> 3, e0 = (g & 7) * 8;
            *(bf16x8*)&W_lds[r * FSTR + e0] =
                *(const bf16x8*)(wb + (size_t)(col0 + r) * DMODEL + kt * 64 + e0);
        }
        __syncthreads();

        bf16x8 af[2][2];
        #pragma unroll
        for (int ri = 0; ri < 2; ++ri) {
            af[ri][0] = *(const bf16x8*)&X_lds[(wave * 32 + ri * 16 + lrow) * FSTR + quad * 8];
            af[ri][1] = *(const bf16x8*)&X_lds[(wave * 32 + ri * 16 + lrow) * FSTR + 32 + quad * 8];
        }
        #pragma unroll
        for (int cj = 0; cj < 4; ++cj) {
            const bf16x8 bf0 = *(const bf16x8*)&W_lds[(cj * 16 + lrow) * FSTR + quad * 8];
            const bf16x8 bf1 = *(const bf16x8*)&W_lds[(cj * 16 + lrow) * FSTR + 32 + quad * 8];
            #pragma unroll
            for (int ri = 0; ri < 2; ++ri) {
                acc[ri][cj] = __builtin_amdgcn_mfma_f32_16x16x32_bf16(af[ri][0], bf0, acc[ri][cj], 0, 0, 0);
                acc[ri][cj] = __builtin_amdgcn_mfma_f32_16x16x32_bf16(af[ri][1], bf1, acc[ri][cj], 0, 0, 0);
            }
        }
    }

    #pragma unroll
    for (int ri = 0; ri < 2; ++ri)
        #pragma unroll
        for (int cj = 0; cj < 4; ++cj) {
            const int col = col0 + cj * 16 + lrow;
            const float bv = bias[col];
            #pragma unroll
            for (int r = 0; r < 4; ++r)
                out[(size_t)(row0 + wave * 32 + ri * 16 + quad * 4 + r) * DMODEL + col] = acc[ri][cj][r] + bv;
        }
}

extern "C" void kernel_launch(void* const* d_in, const int* in_sizes, int n_in,
                              void* d_out, int out_size, void* d_ws, size_t ws_size,
                              hipStream_t stream) {
    const float* q   = (const float*)d_in[0];
    const float* k   = (const float*)d_in[1];
    const float* v   = (const float*)d_in[2];
    const int*   m   = (const int*)d_in[3];
    const float* fcw = (const float*)d_in[4];
    const float* fcb = (const float*)d_in[5];
    float* out = (float*)d_out;

    char* ws = (char*)d_ws;
    u16*   kbuf  = (u16*)(ws);                     // 8 MB  bf16 [2][16][2048][64]
    u16*   vtbuf = (u16*)(ws + (8u  << 20));       // 8 MB  bf16 [2][16][64][2048]
    u16*   wbuf  = (u16*)(ws + (16u << 20));       // 2 MB  bf16 [1024][1024]
    u16*   xbuf  = (u16*)(ws + (18u << 20));       // 8 MB  bf16 [4096][1024]
    float* maskf = (float*)(ws + (26u << 20));     // 16 KB float bias [2][2048]
    float* opart = (float*)(ws + (27u << 20));     // up to 64 MB fp32 [NSPLIT][4096][1024]
    // lpart placed after opart depending on split count
    const bool split4 = ws_size >= (93u << 20);
    const bool split2 = ws_size >= (60u << 20);

    pack_all<<<dim3(3585), dim3(256), 0, stream>>>(k, fcw, v, m, kbuf, wbuf, vtbuf, maskf);
    if (split4) {
        float* lpart = (float*)(ws + (91u << 20)); // 1 MB fp32 [4][4096][16]
        attn_kernel<4><<<dim3(2048), dim3(256), 0, stream>>>(q, kbuf, vtbuf, maskf, xbuf, opart, lpart);
        reduce_norm<4><<<dim3(2048), dim3(256), 0, stream>>>(opart, lpart, xbuf);
    } else if (split2) {
        float* lpart = (float*)(ws + (59u << 20)); // 512 KB fp32 [2][4096][16]
        attn_kernel<2><<<dim3(1024), dim3(256), 0, stream>>>(q, kbuf, vtbuf, maskf, xbuf, opart, lpart);
        reduce_norm<2><<<dim3(2048), dim3(256), 0, stream>>>(opart, lpart, xbuf);
    } else {
        float* lpart = (float*)(ws + (59u << 20));
        attn_kernel<1><<<dim3(512), dim3(256), 0, stream>>>(q, kbuf, vtbuf, maskf, xbuf, opart, lpart);
    }
    fc_kernel<<<dim3(512), dim3(256), 0, stream>>>(xbuf, wbuf, fcb, out);
}

// Round 6
// 179.035 us; speedup vs baseline: 1.2349x; 1.1738x over previous
//
#include <hip/hip_runtime.h>
#include <hip/hip_bf16.h>

#define SEQL 2048
#define DMODEL 1024

typedef short bf16x8 __attribute__((ext_vector_type(8)));
typedef short bf16x4 __attribute__((ext_vector_type(4)));
typedef float f32x4 __attribute__((ext_vector_type(4)));
typedef unsigned short u16;

__device__ __forceinline__ u16 f2bf(float f) {
    union { float f; unsigned u; } v; v.f = f;
    unsigned r = v.u + 0x7FFFu + ((v.u >> 16) & 1u);
    return (u16)(r >> 16);
}

// async 16B global->LDS copy (global_load_lds_dwordx4)
__device__ __forceinline__ void async16(u16* lds, const u16* g) {
    __builtin_amdgcn_global_load_lds(
        (const __attribute__((address_space(1))) unsigned int*)g,
        (__attribute__((address_space(3))) unsigned int*)lds,
        16, 0, 0);
}

// ============================================================================
// Fragment-ordered layouts. Frag = 64 lanes x 8 elems = 512 elems (1 KB).
// All frags use: lane = m + 16*quad, elems j=0..7 where (m = non-k index,
// k = quad*8+j) — the verified 16x16x32 A/B operand layout.
//
// K  image per (n,h,kt64): [st 0..3][f 0..1] frag; key=st*16+m, d=f*32+q*8+j
// Vt image per (n,h,kt64): [t4 0..3][kk 0..1] frag; d=t4*16+m, key=kk*32+q*8+j
// W  image per (cb,kt64):  [cj 0..3][f 0..1] frag; col=cj*16+m, k=f*32+q*8+j
// X  image per (rb128,kt64): [rt 0..7][f 0..1] frag; row=rt*16+m, k=f*32+q*8+j
// ============================================================================

// ---------- pack all inputs ----------
// b < 2048 : K -> frag-ordered bf16 ; b < 2560 : W -> frag-ordered bf16
// b < 3584 : V -> frag-ordered transposed bf16 ; b == 3584 : mask -> bias
#define TSTR 72

__global__ __launch_bounds__(256) void pack_all(
    const float* __restrict__ kg, const float* __restrict__ wg,
    const float* __restrict__ vg, const int* __restrict__ mg,
    u16* __restrict__ kb, u16* __restrict__ wb, u16* __restrict__ vtb,
    float* __restrict__ maskf)
{
    __shared__ __align__(16) u16 T[64 * TSTR];
    const int b = blockIdx.x, t = threadIdx.x;
    u16 o[8];
    if (b < 2048) {
        const int e0 = (b * 256 + t) * 8;
        const int n = e0 >> 21;
        const int s = (e0 >> 10) & 2047;
        const int dm = e0 & 1023, h = dm >> 6, d0 = dm & 63;
        const float4 x0 = *(const float4*)(kg + e0);
        const float4 x1 = *(const float4*)(kg + e0 + 4);
        o[0]=f2bf(x0.x); o[1]=f2bf(x0.y); o[2]=f2bf(x0.z); o[3]=f2bf(x0.w);
        o[4]=f2bf(x1.x); o[5]=f2bf(x1.y); o[6]=f2bf(x1.z); o[7]=f2bf(x1.w);
        const int kt = s >> 6, st = (s >> 4) & 3, m = s & 15;
        const int f = d0 >> 5, qd = (d0 >> 3) & 3;
        u16* dst = kb + ((size_t)((n * 16 + h) * 32 + kt)) * 4096
                      + (st * 2 + f) * 512 + (m + 16 * qd) * 8;
        *(bf16x8*)dst = *(bf16x8*)o;
    } else if (b < 2560) {
        const int e0 = ((b - 2048) * 256 + t) * 8;
        const int col = e0 >> 10, k0 = e0 & 1023;
        const float4 x0 = *(const float4*)(wg + e0);
        const float4 x1 = *(const float4*)(wg + e0 + 4);
        o[0]=f2bf(x0.x); o[1]=f2bf(x0.y); o[2]=f2bf(x0.z); o[3]=f2bf(x0.w);
        o[4]=f2bf(x1.x); o[5]=f2bf(x1.y); o[6]=f2bf(x1.z); o[7]=f2bf(x1.w);
        const int cb = col >> 6, cj = (col >> 4) & 3, m = col & 15;
        const int kt = k0 >> 6, f = (k0 >> 5) & 1, qd = (k0 >> 3) & 3;
        u16* dst = wb + ((size_t)((cb * 16 + kt) * 8 + cj * 2 + f)) * 512
                      + (m + 16 * qd) * 8;
        *(bf16x8*)dst = *(bf16x8*)o;
    } else if (b < 3584) {
        const int bb = b - 2560;
        const int kt = bb & 31, h = (bb >> 5) & 15, n = bb >> 9;
        {
            const int s = t >> 2, d0 = (t & 3) * 16;
            const float* src = vg + ((size_t)(n * SEQL + kt * 64 + s) * DMODEL) + h * 64 + d0;
            u16 w16[16];
            #pragma unroll
            for (int j = 0; j < 16; ++j) w16[j] = f2bf(src[j]);
            *(bf16x8*)&T[s * TSTR + d0]     = *(bf16x8*)&w16[0];
            *(bf16x8*)&T[s * TSTR + d0 + 8] = *(bf16x8*)&w16[8];
        }
        __syncthreads();
        {
            const int d = t >> 2, k0 = (t & 3) * 16;
            u16 w16[16];
            #pragma unroll
            for (int j = 0; j < 16; ++j) w16[j] = T[(k0 + j) * TSTR + d];
            const int t4 = d >> 4, dr = d & 15;
            u16* base = vtb + ((size_t)((n * 16 + h) * 32 + kt)) * 4096;
            #pragma unroll
            for (int g = 0; g < 2; ++g) {
                const int key0 = k0 + g * 8;
                const int kk = key0 >> 5, qk = (key0 >> 3) & 3;
                *(bf16x8*)(base + (t4 * 2 + kk) * 512 + (dr + 16 * qk) * 8)
                    = *(bf16x8*)&w16[g * 8];
            }
        }
    } else {
        #pragma unroll
        for (int i = 0; i < 16; ++i) {
            const int idx = t * 16 + i;
            maskf[idx] = mg[idx] ? 0.0f : -1.0e5f;
        }
    }
}

// ---------- attention: QT=128, KT=64, S^T trick, streaming softmax, split-K ----
#define OSPLIT 4194304   // fp32 elems per O-partial split (16 MB)
#define LSPLIT 65536     // fp32 elems per l-partial split

template<int NSPLIT>
__global__ __launch_bounds__(256) void attn_kernel(
    const float* __restrict__ qg, const u16* __restrict__ kb,
    const u16* __restrict__ vtb, const float* __restrict__ maskf,
    u16* __restrict__ xb, float* __restrict__ opart, float* __restrict__ lpart)
{
    // K 4096 | V 4096 | P 8192  (all frag-ordered, 32 KB total)
    __shared__ __align__(16) u16 SM[16384];
    u16* const K_lds = SM;
    u16* const V_lds = SM + 4096;
    u16* const P_lds = SM + 8192;

    const int blk = blockIdx.x;            // qblk(16) x h(16) x n(2) x split
    const int qblk = blk & 15;
    const int h = (blk >> 4) & 15;
    const int n = (blk >> 8) & 1;
    const int split = blk >> 9;
    const int tid = threadIdx.x;
    const int wave = tid >> 6, lane = tid & 63;
    const int lrow = lane & 15, quad = lane >> 4;
    const int q0 = qblk * 128;

    // Q fragments ([q=lane&15][d=quad*8+j]); 2 q-tiles per wave
    bf16x8 qf[2][2];
    #pragma unroll
    for (int qi = 0; qi < 2; ++qi) {
        const float* qp = qg + ((size_t)(n * SEQL + q0 + wave * 32 + qi * 16 + lrow) * DMODEL) + h * 64 + quad * 8;
        #pragma unroll
        for (int f = 0; f < 2; ++f) {
            const float4 a = *(const float4*)(qp + f * 32);
            const float4 c = *(const float4*)(qp + f * 32 + 4);
            u16* dst = (u16*)&qf[qi][f];
            dst[0]=f2bf(a.x); dst[1]=f2bf(a.y); dst[2]=f2bf(a.z); dst[3]=f2bf(a.w);
            dst[4]=f2bf(c.x); dst[5]=f2bf(c.y); dst[6]=f2bf(c.z); dst[7]=f2bf(c.w);
        }
    }

    bf16x8 onesf;
    #pragma unroll
    for (int j = 0; j < 8; ++j) ((u16*)&onesf)[j] = 0x3F80;

    f32x4 oacc[2][4];
    f32x4 lacc[2];
    #pragma unroll
    for (int qi = 0; qi < 2; ++qi) {
        lacc[qi] = (f32x4){0.f, 0.f, 0.f, 0.f};
        #pragma unroll
        for (int t4 = 0; t4 < 4; ++t4) oacc[qi][t4] = (f32x4){0.f, 0.f, 0.f, 0.f};
    }

    const u16* ksrc0 = kb  + ((size_t)(n * 16 + h)) * 131072;  // 32 kt * 4096
    const u16* vsrc0 = vtb + ((size_t)(n * 16 + h)) * 131072;
    const float* mrow = maskf + n * SEQL;

    const int ktlo = split * (32 / NSPLIT);
    const int kthi = ktlo + (32 / NSPLIT);

    for (int kt = ktlo; kt < kthi; ++kt) {
        __syncthreads();
        {
            const u16* ks = ksrc0 + (size_t)kt * 4096;
            const u16* vs = vsrc0 + (size_t)kt * 4096;
            #pragma unroll
            for (int i = 0; i < 2; ++i) {
                const int ch = tid + i * 256;          // 512 chunks of 16B each
                async16(&K_lds[ch * 8], ks + ch * 8);
                async16(&V_lds[ch * 8], vs + ch * 8);
            }
        }
        __syncthreads();

        // S^T = K Q^T : C col = q (lane&15), C rows = key (quad*4+r)
        #pragma unroll
        for (int st = 0; st < 4; ++st) {
            const bf16x8 kf0 = *(const bf16x8*)&K_lds[(st * 2 + 0) * 512 + lane * 8];
            const bf16x8 kf1 = *(const bf16x8*)&K_lds[(st * 2 + 1) * 512 + lane * 8];
            const f32x4 mv = *(const f32x4*)&mrow[kt * 64 + st * 16 + quad * 4];
            // P-write frag coords for key = st*16 + quad*4 + r
            const int kk = st >> 1;
            const int qk = (st & 1) * 2 + (quad >> 1);
            const int j0 = (quad & 1) * 4;
            #pragma unroll
            for (int qi = 0; qi < 2; ++qi) {
                f32x4 sa = (f32x4){0.f, 0.f, 0.f, 0.f};
                sa = __builtin_amdgcn_mfma_f32_16x16x32_bf16(kf0, qf[qi][0], sa, 0, 0, 0);
                sa = __builtin_amdgcn_mfma_f32_16x16x32_bf16(kf1, qf[qi][1], sa, 0, 0, 0);
                float e0v = __expf(fmaf(sa[0], 0.03125f, mv[0]));
                float e1v = __expf(fmaf(sa[1], 0.03125f, mv[1]));
                float e2v = __expf(fmaf(sa[2], 0.03125f, mv[2]));
                float e3v = __expf(fmaf(sa[3], 0.03125f, mv[3]));
                __hip_bfloat162 h0 = __float22bfloat162_rn(make_float2(e0v, e1v));
                __hip_bfloat162 h1 = __float22bfloat162_rn(make_float2(e2v, e3v));
                union { unsigned u[2]; bf16x4 v; } pk;
                pk.u[0] = *(unsigned*)&h0;
                pk.u[1] = *(unsigned*)&h1;
                *(bf16x4*)&P_lds[wave * 2048 + (qi * 2 + kk) * 512 + (lrow + 16 * qk) * 8 + j0] = pk.v;
            }
        }
        asm volatile("s_waitcnt lgkmcnt(0)" ::: "memory");

        bf16x8 vf[4][2];
        #pragma unroll
        for (int t4 = 0; t4 < 4; ++t4) {
            vf[t4][0] = *(const bf16x8*)&V_lds[(t4 * 2 + 0) * 512 + lane * 8];
            vf[t4][1] = *(const bf16x8*)&V_lds[(t4 * 2 + 1) * 512 + lane * 8];
        }
        #pragma unroll
        for (int qi = 0; qi < 2; ++qi) {
            const bf16x8 pf0 = *(const bf16x8*)&P_lds[wave * 2048 + (qi * 2 + 0) * 512 + lane * 8];
            const bf16x8 pf1 = *(const bf16x8*)&P_lds[wave * 2048 + (qi * 2 + 1) * 512 + lane * 8];
            lacc[qi] = __builtin_amdgcn_mfma_f32_16x16x32_bf16(pf0, onesf, lacc[qi], 0, 0, 0);
            lacc[qi] = __builtin_amdgcn_mfma_f32_16x16x32_bf16(pf1, onesf, lacc[qi], 0, 0, 0);
            #pragma unroll
            for (int t4 = 0; t4 < 4; ++t4) {
                oacc[qi][t4] = __builtin_amdgcn_mfma_f32_16x16x32_bf16(pf0, vf[t4][0], oacc[qi][t4], 0, 0, 0);
                oacc[qi][t4] = __builtin_amdgcn_mfma_f32_16x16x32_bf16(pf1, vf[t4][1], oacc[qi][t4], 0, 0, 0);
            }
        }
    }

    if (NSPLIT == 1) {
        // fallback: write frag-ordered bf16 X directly (scalar scatter)
        #pragma unroll
        for (int qi = 0; qi < 2; ++qi)
            #pragma unroll
            for (int r = 0; r < 4; ++r) {
                const float rinv = 1.0f / lacc[qi][r];
                const int row = n * SEQL + q0 + wave * 32 + qi * 16 + quad * 4 + r;
                const int rb = row >> 7, rt = (row >> 4) & 7, m = row & 15;
                #pragma unroll
                for (int t4 = 0; t4 < 4; ++t4) {
                    const int f = t4 >> 1;
                    const int qd = (t4 & 1) * 2 + (lrow >> 3);
                    xb[((size_t)((rb * 16 + h) * 16 + rt * 2 + f)) * 512
                       + (m + 16 * qd) * 8 + (lrow & 7)] = f2bf(oacc[qi][t4][r] * rinv);
                }
            }
    } else {
        #pragma unroll
        for (int qi = 0; qi < 2; ++qi) {
            #pragma unroll
            for (int r = 0; r < 4; ++r) {
                const int q = q0 + wave * 32 + qi * 16 + quad * 4 + r;
                float* op = opart + (size_t)split * OSPLIT + (size_t)(n * SEQL + q) * DMODEL + h * 64 + lrow;
                #pragma unroll
                for (int t4 = 0; t4 < 4; ++t4)
                    op[t4 * 16] = oacc[qi][t4][r];
                if (lrow == 0)
                    lpart[split * LSPLIT + (n * SEQL + q) * 16 + h] = lacc[qi][r];
            }
        }
    }
}

// ---------- split-K reduce + normalize -> frag-ordered bf16 X ----------
template<int NSPLIT>
__global__ __launch_bounds__(256) void reduce_norm(
    const float* __restrict__ opart, const float* __restrict__ lpart,
    u16* __restrict__ xb)
{
    const int gid = blockIdx.x * 256 + threadIdx.x;   // 524288 threads
    const int e0 = gid * 8;
    const int row = e0 >> 10, k0 = e0 & 1023, h = k0 >> 6;
    float lsum = 0.f;
    #pragma unroll
    for (int s = 0; s < NSPLIT; ++s) lsum += lpart[s * LSPLIT + row * 16 + h];
    const float rinv = 1.0f / lsum;
    float a[8] = {0.f,0.f,0.f,0.f,0.f,0.f,0.f,0.f};
    #pragma unroll
    for (int s = 0; s < NSPLIT; ++s) {
        const float4 x0 = *(const float4*)(opart + (size_t)s * OSPLIT + e0);
        const float4 x1 = *(const float4*)(opart + (size_t)s * OSPLIT + e0 + 4);
        a[0]+=x0.x; a[1]+=x0.y; a[2]+=x0.z; a[3]+=x0.w;
        a[4]+=x1.x; a[5]+=x1.y; a[6]+=x1.z; a[7]+=x1.w;
    }
    u16 o[8];
    #pragma unroll
    for (int j = 0; j < 8; ++j) o[j] = f2bf(a[j] * rinv);
    // frag-ordered X address
    const int rb = row >> 7, rt = (row >> 4) & 7, m = row & 15;
    const int kt = k0 >> 6, f = (k0 >> 5) & 1, qd = (k0 >> 3) & 3;
    *(bf16x8*)(xb + ((size_t)((rb * 16 + kt) * 16 + rt * 2 + f)) * 512
                  + (m + 16 * qd) * 8) = *(bf16x8*)o;
}

// ---------- FC: out = X @ W^T + b, 128x64 tile, BK=64, frag-ordered, async ----
__global__ __launch_bounds__(256) void fc_kernel(
    const u16* __restrict__ xb, const u16* __restrict__ wb,
    const float* __restrict__ bias, float* __restrict__ out)
{
    // X 8192 | W 4096 (24 KB)
    __shared__ __align__(16) u16 SM[12288];
    u16* const X_lds = SM;
    u16* const W_lds = SM + 8192;

    const int blk = blockIdx.x;          // 32 rowblocks x 16 colblocks = 512
    const int cb = blk & 15, rb = blk >> 4;
    const int tid = threadIdx.x;
    const int wave = tid >> 6, lane = tid & 63;
    const int lrow = lane & 15, quad = lane >> 4;

    f32x4 acc[2][4];
    #pragma unroll
    for (int ri = 0; ri < 2; ++ri)
        #pragma unroll
        for (int cj = 0; cj < 4; ++cj) acc[ri][cj] = (f32x4){0.f, 0.f, 0.f, 0.f};

    for (int kt = 0; kt < 16; ++kt) {
        __syncthreads();
        {
            const u16* xs = xb + ((size_t)(rb * 16 + kt)) * 8192;
            const u16* ws = wb + ((size_t)(cb * 16 + kt)) * 4096;
            #pragma unroll
            for (int i = 0; i < 4; ++i) {
                const int ch = tid + i * 256;          // 1024 chunks
                async16(&X_lds[ch * 8], xs + ch * 8);
            }
            #pragma unroll
            for (int i = 0; i < 2; ++i) {
                const int ch = tid + i * 256;          // 512 chunks
                async16(&W_lds[ch * 8], ws + ch * 8);
            }
        }
        __syncthreads();

        bf16x8 af[2][2];
        #pragma unroll
        for (int ri = 0; ri < 2; ++ri) {
            af[ri][0] = *(const bf16x8*)&X_lds[((wave * 2 + ri) * 2 + 0) * 512 + lane * 8];
            af[ri][1] = *(const bf16x8*)&X_lds[((wave * 2 + ri) * 2 + 1) * 512 + lane * 8];
        }
        #pragma unroll
        for (int cj = 0; cj < 4; ++cj) {
            const bf16x8 bf0 = *(const bf16x8*)&W_lds[(cj * 2 + 0) * 512 + lane * 8];
            const bf16x8 bf1 = *(const bf16x8*)&W_lds[(cj * 2 + 1) * 512 + lane * 8];
            #pragma unroll
            for (int ri = 0; ri < 2; ++ri) {
                acc[ri][cj] = __builtin_amdgcn_mfma_f32_16x16x32_bf16(af[ri][0], bf0, acc[ri][cj], 0, 0, 0);
                acc[ri][cj] = __builtin_amdgcn_mfma_f32_16x16x32_bf16(af[ri][1], bf1, acc[ri][cj], 0, 0, 0);
            }
        }
    }

    const int row0 = rb * 128, col0 = cb * 64;
    #pragma unroll
    for (int ri = 0; ri < 2; ++ri)
        #pragma unroll
        for (int cj = 0; cj < 4; ++cj) {
            const int col = col0 + cj * 16 + lrow;
            const float bv = bias[col];
            #pragma unroll
            for (int r = 0; r < 4; ++r)
                out[(size_t)(row0 + wave * 32 + ri * 16 + quad * 4 + r) * DMODEL + col] = acc[ri][cj][r] + bv;
        }
}

extern "C" void kernel_launch(void* const* d_in, const int* in_sizes, int n_in,
                              void* d_out, int out_size, void* d_ws, size_t ws_size,
                              hipStream_t stream) {
    const float* q   = (const float*)d_in[0];
    const float* k   = (const float*)d_in[1];
    const float* v   = (const float*)d_in[2];
    const int*   m   = (const int*)d_in[3];
    const float* fcw = (const float*)d_in[4];
    const float* fcb = (const float*)d_in[5];
    float* out = (float*)d_out;

    char* ws = (char*)d_ws;
    u16*   kbuf  = (u16*)(ws);                     // 8 MB  frag-ordered K
    u16*   vtbuf = (u16*)(ws + (8u  << 20));       // 8 MB  frag-ordered V^T
    u16*   wbuf  = (u16*)(ws + (16u << 20));       // 2 MB  frag-ordered W
    u16*   xbuf  = (u16*)(ws + (18u << 20));       // 8 MB  frag-ordered X
    float* maskf = (float*)(ws + (26u << 20));     // 16 KB float bias [2][2048]
    float* opart = (float*)(ws + (27u << 20));     // 32 MB fp32 [2][4096][1024]
    float* lpart = (float*)(ws + (59u << 20));     // 512 KB fp32 [2][4096][16]
    const bool split2 = ws_size >= (60u << 20);

    pack_all<<<dim3(3585), dim3(256), 0, stream>>>(k, fcw, v, m, kbuf, wbuf, vtbuf, maskf);
    if (split2) {
        attn_kernel<2><<<dim3(1024), dim3(256), 0, stream>>>(q, kbuf, vtbuf, maskf, xbuf, opart, lpart);
        reduce_norm<2><<<dim3(2048), dim3(256), 0, stream>>>(opart, lpart, xbuf);
    } else {
        attn_kernel<1><<<dim3(512), dim3(256), 0, stream>>>(q, kbuf, vtbuf, maskf, xbuf, opart, lpart);
    }
    fc_kernel<<<dim3(512), dim3(256), 0, stream>>>(xbuf, wbuf, fcb, out);
}